// Round 1
// 230.728 us; speedup vs baseline: 1.0228x; 1.0228x over previous
//
#include <hip/hip_runtime.h>
#include <hip/hip_bf16.h>
#include <math.h>

#define B_ 2
#define T_ 2048
#define D_ 1024
#define H_ 16
#define QSCALE (0.03125f * 1.44269504088896f)  // 1/sqrt(1024) * log2(e)

typedef _Float16 f16;
using f16x4 = __attribute__((ext_vector_type(4))) _Float16;
using f16x8 = __attribute__((ext_vector_type(8))) _Float16;
using f32x4 = __attribute__((ext_vector_type(4))) float;

__device__ __forceinline__ void gl16(const void* g, void* l) {
  __builtin_amdgcn_global_load_lds(
      (__attribute__((address_space(1))) void*)g,
      (__attribute__((address_space(3))) void*)l, 16, 0, 0);
}

// ---------------------------------------------------------------------------
// prep: fused cvt_x (0..6143) + cvt_w transpose (6144..7167) + pack_bias
// (7168..7183) + mask scan -> idx/inv/nk + khc pad-row zeroing (7184..7185)
// ---------------------------------------------------------------------------
__global__ __launch_bounds__(256) void prep(
    const float* __restrict__ q, const float* __restrict__ k,
    const float* __restrict__ v, const int* __restrict__ mask,
    const float* __restrict__ Wq, const float* __restrict__ Wk,
    const float* __restrict__ Wv, const float* __restrict__ Wo,
    const float* __restrict__ bq, const float* __restrict__ bk,
    const float* __restrict__ bv, const float* __restrict__ bo,
    f16* __restrict__ xqkv, f16* __restrict__ Wt, float* __restrict__ bias,
    int* __restrict__ idx, int* __restrict__ inv, int* __restrict__ nk,
    f16* __restrict__ khc) {
  __shared__ float sh[64][65];
  const int bid = blockIdx.x;
  const int tid = threadIdx.x;

  if (bid < 6144) {  // ---- cvt_x: fp32 -> f16 ----
    const int z = bid / 2048;
    const float* src = (z == 0) ? q : (z == 1) ? k : v;
    const size_t i = ((size_t)(bid % 2048) * 256 + tid) * 8;
    float4 a = *(const float4*)(src + i);
    float4 b = *(const float4*)(src + i + 4);
    f16x8 o;
    o[0] = (f16)a.x; o[1] = (f16)a.y; o[2] = (f16)a.z; o[3] = (f16)a.w;
    o[4] = (f16)b.x; o[5] = (f16)b.y; o[6] = (f16)b.z; o[7] = (f16)b.w;
    *(f16x8*)(xqkv + (size_t)z * 4194304 + i) = o;
  } else if (bid < 7168) {  // ---- cvt_w: W[K][N] fp32 -> Wt[N][K] f16 ----
    const int id = bid - 6144;
    const int z = id >> 8;
    const int k0 = ((id >> 4) & 15) * 64, n0 = (id & 15) * 64;
    const float* W = (z == 0) ? Wq : (z == 1) ? Wk : (z == 2) ? Wv : Wo;
    const int r = tid >> 2, c0 = (tid & 3) * 16;
#pragma unroll
    for (int i = 0; i < 4; ++i)
      *(float4*)&sh[r][c0 + 4 * i] =
          *(const float4*)&W[(size_t)(k0 + r) * 1024 + n0 + c0 + 4 * i];
    __syncthreads();
    f16 tmp[16];
#pragma unroll
    for (int i = 0; i < 16; ++i) tmp[i] = (f16)sh[c0 + i][r];
    f16* dst = Wt + (size_t)z * 1048576 + (size_t)(n0 + r) * 1024 + k0 + c0;
    *(f16x8*)dst = *(f16x8*)&tmp[0];
    *(f16x8*)(dst + 8) = *(f16x8*)&tmp[8];
  } else if (bid < 7184) {  // ---- pack_bias ----
    const int i = (bid - 7168) * 256 + tid;
    const int z = i >> 10;
    const float* s = (z == 0) ? bq : (z == 1) ? bk : (z == 2) ? bv : bo;
    bias[i] = s[i & 1023];
  } else {  // ---- mask scan + inverse map + khc pad zero, one block/batch ----
    const int b = bid - 7184;
    int* cnt = (int*)sh;
    int loc[8];
    int c = 0;
#pragma unroll
    for (int i = 0; i < 8; ++i) {
      loc[i] = mask[b * T_ + tid * 8 + i];
      c += loc[i];
    }
    cnt[tid] = c;
    __syncthreads();
    for (int off = 1; off < 256; off <<= 1) {
      int vsh = (tid >= off) ? cnt[tid - off] : 0;
      __syncthreads();
      cnt[tid] += vsh;
      __syncthreads();
    }
    int pos = cnt[tid] - c;  // exclusive prefix
#pragma unroll
    for (int i = 0; i < 8; ++i) {
      const int t = tid * 8 + i;
      if (loc[i]) {
        idx[b * T_ + pos] = t;
        inv[b * T_ + t] = pos;
        ++pos;
      } else {
        inv[b * T_ + t] = -1;
      }
    }
    const int n = cnt[255];
    if (tid == 255) nk[b] = n;
    // zero pad rows n..nkt*64-1 of khc (gemm writes only rows < n)
    const int nkt = (n + 63) >> 6;
    const int npadrows = (nkt << 6) - n;
    uint4 z4 = {0u, 0u, 0u, 0u};
    f16* base = khc + ((size_t)b * T_ + n) * D_;
    for (int i = tid; i < npadrows * 128; i += 256)
      *(uint4*)(base + (size_t)i * 8) = z4;
  }
}

// ---------------------------------------------------------------------------
// m97-style GEMM: C[M,N] = X[M,K] @ Wt[N,K]^T + bias, f16 in.
// TM x 128 tile, BK=32, global_load_lds width-16 staging, 4 waves (2x2).
// z selects (X slice, Wt slice, bias slice, C pointer). z==0 applies qscale.
// z==1 with inv != nullptr: scatter rows through inv (K compaction), masked
// rows dropped (pad rows pre-zeroed by prep).
// ---------------------------------------------------------------------------
template <int TM, typename OT>
__global__ __launch_bounds__(256) void gemm_bt(
    const f16* __restrict__ Xb, const f16* __restrict__ Wtb,
    const float* __restrict__ biasb, void* __restrict__ C0,
    void* __restrict__ C1, void* __restrict__ C2,
    const int* __restrict__ inv, int M, int N, int K, float qscale) {
  constexpr int FM = TM / 32;
  __shared__ __align__(16) f16 As[TM * 32];
  __shared__ __align__(16) f16 Bs[128 * 32];
  const int z = blockIdx.z;
  const f16* X  = Xb  + (size_t)z * M * K;
  const f16* Wt = Wtb + (size_t)z * N * K;
  const float* bias = biasb + (size_t)z * N;
  OT* C = (OT*)((z == 0) ? C0 : (z == 1) ? C1 : C2);
  const float scl = (z == 0) ? qscale : 1.f;

  const int tid = threadIdx.x;
  const int wave = tid >> 6, lane = tid & 63;
  const int quad = lane >> 4, l16 = lane & 15;
  const int wm = wave & 1, wn = wave >> 1;
  const int m0 = blockIdx.y * TM, n0 = blockIdx.x * 128;

  f32x4 acc[FM][4] = {};

  const f16* asrc = X  + (size_t)(m0 + (tid >> 2)) * K + (tid & 3) * 8;
  const f16* bsrc = Wt + (size_t)(n0 + (tid >> 2)) * K + (tid & 3) * 8;
  char* aldst = (char*)As + tid * 16;
  char* bldst = (char*)Bs + tid * 16;
  const size_t rstep = (size_t)64 * K;

  const int NK = K >> 5;
  for (int kt = 0; kt < NK; ++kt) {
    if (kt) __syncthreads();
    gl16(asrc, aldst);
    if constexpr (TM == 128) gl16(asrc + rstep, aldst + 4096);
    gl16(bsrc, bldst);
    gl16(bsrc + rstep, bldst + 4096);
    asrc += 32; bsrc += 32;
    __syncthreads();

    f16x8 af[FM], bf[4];
#pragma unroll
    for (int t = 0; t < FM; ++t)
      af[t] = *(const f16x8*)&As[((TM / 2) * wm + 16 * t + l16) * 32 + quad * 8];
#pragma unroll
    for (int t = 0; t < 4; ++t)
      bf[t] = *(const f16x8*)&Bs[(64 * wn + 16 * t + l16) * 32 + quad * 8];
#pragma unroll
    for (int i = 0; i < FM; ++i)
#pragma unroll
      for (int j = 0; j < 4; ++j)
        acc[i][j] = __builtin_amdgcn_mfma_f32_16x16x32_f16(af[i], bf[j], acc[i][j], 0, 0, 0);
  }

  const int cm = m0 + (TM / 2) * wm + 4 * quad;
  const int cn = n0 + 64 * wn + l16;
  float bv[4];
#pragma unroll
  for (int tn = 0; tn < 4; ++tn) bv[tn] = bias[cn + 16 * tn];

  if (inv != nullptr && z == 1) {  // K-compaction scatter
    const int bb = m0 >> 11;
#pragma unroll
    for (int tm = 0; tm < FM; ++tm) {
#pragma unroll
      for (int r = 0; r < 4; ++r) {
        const int m = cm + 16 * tm + r;
        const int j = inv[m];
        if (j >= 0) {
          OT* row = C + ((size_t)(bb << 11) + j) * N;
#pragma unroll
          for (int tn = 0; tn < 4; ++tn)
            row[cn + 16 * tn] = (OT)(acc[tm][tn][r] + bv[tn]);
        }
      }
    }
  } else {
#pragma unroll
    for (int tm = 0; tm < FM; ++tm)
#pragma unroll
      for (int r = 0; r < 4; ++r) {
        OT* row = C + (size_t)(cm + 16 * tm + r) * N;
#pragma unroll
        for (int tn = 0; tn < 4; ++tn)
          row[cn + 16 * tn] = (OT)((acc[tm][tn][r] + bv[tn]) * scl);
      }
  }
}

// ---------------------------------------------------------------------------
// vtrans: gather + transpose V. vhT[bh][dh][j] = vh[b][idx[j]][h*64+dh],
// zeros for pad j; tiles >= nkt untouched (attn never reads them).
// ---------------------------------------------------------------------------
__global__ __launch_bounds__(256) void vtrans(
    const f16* __restrict__ vh, const int* __restrict__ idx,
    const int* __restrict__ nk, f16* __restrict__ vhT) {
  const int tt = blockIdx.x, bh = blockIdx.y;
  const int b = bh >> 4, h = bh & 15;
  const int n = nk[b];
  const int nkt = (n + 63) >> 6;
  if (tt >= nkt) return;
  __shared__ f16 t[64][72];
  const int tid = threadIdx.x;
  const int r = tid >> 2, cq = 16 * (tid & 3);

  const int j = tt * 64 + r;
  uint4 v0 = {0u, 0u, 0u, 0u}, v1 = {0u, 0u, 0u, 0u};
  if (j < n) {
    const int tsrc = idx[b * T_ + j];
    const uint4* src = (const uint4*)(vh + ((size_t)b * T_ + tsrc) * D_ + h * 64 + cq);
    v0 = src[0]; v1 = src[1];
  }
  *(uint4*)&t[r][cq]     = v0;
  *(uint4*)&t[r][cq + 8] = v1;
  __syncthreads();

  f16 tmp[16];
#pragma unroll
  for (int xx = 0; xx < 16; ++xx) {
    int x = (xx + r) & 15;
    tmp[x] = t[cq + x][r];
  }
  f16* dst = vhT + ((size_t)bh * 64 + r) * T_ + tt * 64 + cq;
  *(uint4*)&dst[0] = *(uint4*)&tmp[0];
  *(uint4*)&dst[8] = *(uint4*)&tmp[8];
}

// ---------------------------------------------------------------------------
// Flash attention over compacted keys. Block = 128 q-rows (grid 16 x 32),
// 512 threads / 8 waves; each wave owns 16 q-rows. vs the 4-wave/32-row
// version: same total work and same 36.9KB LDS, but 16 waves/CU instead of 8
// (grid was the occupancy cap at 2 blocks/CU) -> 2x latency hiding for the
// VALU-heavy softmax. Q frags direct from global, cached in regs (no Qs LDS).
// qh pre-scaled by SCALE*log2e -> P = exp2(S); pad keys contribute p=1,
// corrected via lsum -= npad. P round-trips wave-private LDS strip.
// ---------------------------------------------------------------------------
__global__ __launch_bounds__(512) void attn_mfma(
    const f16* __restrict__ qh, const f16* __restrict__ khc,
    const f16* __restrict__ vhT, const int* __restrict__ nkd,
    f16* __restrict__ oat) {
  __shared__ f16 Ks[64][72];     // [key][dh]
  __shared__ f16 Vt[64][72];     // [dh][key]
  __shared__ f16 Ps[8][16][72];  // per-wave [qrow][key]

  const int qt = blockIdx.x, bh = blockIdx.y;
  const int b = bh >> 4, h = bh & 15;
  const int tid = threadIdx.x;
  const int wave = tid >> 6, lane = tid & 63;
  const int quad = lane >> 4, l16 = lane & 15;
  const int sr = tid >> 3, sq = 8 * (tid & 7);  // 512 thr: 1 uint4 each for K,V

  const int n = nkd[b];
  const int nkt = (n + 63) >> 6;
  const int npad = (nkt << 6) - n;

  // Q fragments direct from global: row qt*128 + wave*16 + l16
  f16x8 qf[2];
  {
    const f16* qp = qh + ((size_t)(b * T_ + qt * 128 + wave * 16 + l16)) * D_ + h * 64 + quad * 8;
    qf[0] = *(const f16x8*)qp;
    qf[1] = *(const f16x8*)(qp + 32);
  }

  float lsum = 0.f;
  f32x4 o[4] = {};

  const f16* kbase = khc + (size_t)b * T_ * D_ + h * 64;
  const f16* vbase = vhT + ((size_t)bh * 64 + sr) * T_;

  uint4 kr, vr;
  auto load_kv = [&](int kt) {
    kr = *(const uint4*)(kbase + (size_t)(kt * 64 + sr) * D_ + sq);
    vr = *(const uint4*)(vbase + kt * 64 + sq);
  };
  if (nkt > 0) load_kv(0);

  for (int kt = 0; kt < nkt; ++kt) {
    *(uint4*)&Ks[sr][sq] = kr;
    *(uint4*)&Vt[sr][sq] = vr;
    __syncthreads();
    if (kt + 1 < nkt) load_kv(kt + 1);  // prefetch next tile into regs

    // ---- S^T = K Q^T : D[m=key][n=qrow] ----
#pragma unroll
    for (int tn = 0; tn < 4; ++tn) {
      f16x8 kf0 = *(const f16x8*)&Ks[16 * tn + l16][quad * 8];
      f16x8 kf1 = *(const f16x8*)&Ks[16 * tn + l16][32 + quad * 8];
      f32x4 s = {0.f, 0.f, 0.f, 0.f};
      s = __builtin_amdgcn_mfma_f32_16x16x32_f16(kf0, qf[0], s, 0, 0, 0);
      s = __builtin_amdgcn_mfma_f32_16x16x32_f16(kf1, qf[1], s, 0, 0, 0);
      float p0 = exp2f(s[0]), p1 = exp2f(s[1]);
      float p2 = exp2f(s[2]), p3 = exp2f(s[3]);
      lsum += (p0 + p1) + (p2 + p3);
      f16x4 pk;
      pk[0] = (f16)p0; pk[1] = (f16)p1; pk[2] = (f16)p2; pk[3] = (f16)p3;
      *(f16x4*)&Ps[wave][l16][16 * tn + 4 * quad] = pk;
    }

    // ---- O += P V ----
    f16x8 pf0 = *(const f16x8*)&Ps[wave][l16][quad * 8];
    f16x8 pf1 = *(const f16x8*)&Ps[wave][l16][32 + quad * 8];
#pragma unroll
    for (int t = 0; t < 4; ++t) {
      f16x8 vf0 = *(const f16x8*)&Vt[16 * t + l16][quad * 8];
      f16x8 vf1 = *(const f16x8*)&Vt[16 * t + l16][32 + quad * 8];
      o[t] = __builtin_amdgcn_mfma_f32_16x16x32_f16(pf0, vf0, o[t], 0, 0, 0);
      o[t] = __builtin_amdgcn_mfma_f32_16x16x32_f16(pf1, vf1, o[t], 0, 0, 0);
    }
    __syncthreads();
  }

  {
    float ls = lsum;
    ls += __shfl_xor(ls, 16);   // quads hold disjoint key subsets
    ls += __shfl_xor(ls, 32);
    ls -= (float)npad;
    const size_t orow = (size_t)(b * T_ + qt * 128 + wave * 16 + 4 * quad);
#pragma unroll
    for (int r = 0; r < 4; ++r) {
      const float iv = 1.f / __shfl(ls, 4 * quad + r);
#pragma unroll
      for (int t = 0; t < 4; ++t)
        oat[(orow + r) * D_ + h * 64 + 16 * t + l16] = (f16)(o[t][r] * iv);
    }
  }
}

// ---------------------------------------------------------------------------
extern "C" void kernel_launch(void* const* d_in, const int* in_sizes, int n_in,
                              void* d_out, int out_size, void* d_ws, size_t ws_size,
                              hipStream_t stream) {
  const float* q  = (const float*)d_in[0];
  const float* k  = (const float*)d_in[1];
  const float* v  = (const float*)d_in[2];
  const int* mask = (const int*)d_in[3];
  const float* Wq = (const float*)d_in[4];
  const float* bq = (const float*)d_in[5];
  const float* Wk = (const float*)d_in[6];
  const float* bk = (const float*)d_in[7];
  const float* Wv = (const float*)d_in[8];
  const float* bv = (const float*)d_in[9];
  const float* Wo = (const float*)d_in[10];
  const float* bo = (const float*)d_in[11];
  float* out = (float*)d_out;

  // ws layout (bytes):
  //  0        xq (8MB)  -> vhT after gemm_qkv
  //  8388608  xk (8MB)  -> oat after gemm_qkv
  //  16777216 xv (8MB)
  //  25165824 Wt (8MB)
  //  33554432 qh (8MB)
  //  41943040 vh (8MB)
  //  50331648 khc (8MB)
  //  58720256 bias(16KB) | idx(16KB) | inv(16KB) | nk(8B)
  char* ws = (char*)d_ws;
  f16* xqkv  = (f16*)(ws);
  f16* Wt    = (f16*)(ws + 25165824);
  f16* qh    = (f16*)(ws + 33554432);
  f16* vh    = (f16*)(ws + 41943040);
  f16* khc   = (f16*)(ws + 50331648);
  float* bsw = (float*)(ws + 58720256);
  int* idx   = (int*)(ws + 58736640);
  int* inv   = (int*)(ws + 58753024);
  int* nk    = (int*)(ws + 58769408);
  f16* vhT   = (f16*)(ws);             // aliases xq (dead after gemm_qkv)
  f16* oat   = (f16*)(ws + 8388608);   // aliases xk (dead after gemm_qkv)

  const int M = B_ * T_;  // 4096
  dim3 blk(256);

  prep<<<dim3(7186), blk, 0, stream>>>(q, k, v, mask, Wq, Wk, Wv, Wo,
                                       bq, bk, bv, bo, xqkv, Wt, bsw,
                                       idx, inv, nk, khc);

  gemm_bt<128, f16><<<dim3(8, 32, 3), blk, 0, stream>>>(
      xqkv, Wt, bsw, qh, khc, vh, inv, M, D_, D_, QSCALE);

  vtrans<<<dim3(32, 32), blk, 0, stream>>>(vh, idx, nk, vhT);

  attn_mfma<<<dim3(16, 32), dim3(512), 0, stream>>>(qh, khc, vhT, nk, oat);

  gemm_bt<64, float><<<dim3(8, 64, 1), blk, 0, stream>>>(
      oat, Wt + 3145728, bsw + 3072, out, out, out, nullptr, M, D_, D_, 1.f);
}

// Round 2
// 224.962 us; speedup vs baseline: 1.0490x; 1.0256x over previous
//
#include <hip/hip_runtime.h>
#include <hip/hip_bf16.h>
#include <math.h>

#define B_ 2
#define T_ 2048
#define D_ 1024
#define H_ 16
#define QSCALE (0.03125f * 1.44269504088896f)  // 1/sqrt(1024) * log2(e)

typedef _Float16 f16;
using f16x4 = __attribute__((ext_vector_type(4))) _Float16;
using f16x8 = __attribute__((ext_vector_type(8))) _Float16;
using f32x4 = __attribute__((ext_vector_type(4))) float;

__device__ __forceinline__ void gl16(const void* g, void* l) {
  __builtin_amdgcn_global_load_lds(
      (__attribute__((address_space(1))) void*)g,
      (__attribute__((address_space(3))) void*)l, 16, 0, 0);
}

// ---------------------------------------------------------------------------
// prep: fused cvt_x (0..6143) + cvt_w transpose (6144..7167) + pack_bias
// (7168..7183) + mask scan -> idx/inv/nk + khc pad-row zeroing (7184..7185)
// ---------------------------------------------------------------------------
__global__ __launch_bounds__(256) void prep(
    const float* __restrict__ q, const float* __restrict__ k,
    const float* __restrict__ v, const int* __restrict__ mask,
    const float* __restrict__ Wq, const float* __restrict__ Wk,
    const float* __restrict__ Wv, const float* __restrict__ Wo,
    const float* __restrict__ bq, const float* __restrict__ bk,
    const float* __restrict__ bv, const float* __restrict__ bo,
    f16* __restrict__ xqkv, f16* __restrict__ Wt, float* __restrict__ bias,
    int* __restrict__ idx, int* __restrict__ inv, int* __restrict__ nk,
    f16* __restrict__ khc) {
  __shared__ float sh[64][65];
  const int bid = blockIdx.x;
  const int tid = threadIdx.x;

  if (bid < 6144) {  // ---- cvt_x: fp32 -> f16 ----
    const int z = bid / 2048;
    const float* src = (z == 0) ? q : (z == 1) ? k : v;
    const size_t i = ((size_t)(bid % 2048) * 256 + tid) * 8;
    float4 a = *(const float4*)(src + i);
    float4 b = *(const float4*)(src + i + 4);
    f16x8 o;
    o[0] = (f16)a.x; o[1] = (f16)a.y; o[2] = (f16)a.z; o[3] = (f16)a.w;
    o[4] = (f16)b.x; o[5] = (f16)b.y; o[6] = (f16)b.z; o[7] = (f16)b.w;
    *(f16x8*)(xqkv + (size_t)z * 4194304 + i) = o;
  } else if (bid < 7168) {  // ---- cvt_w: W[K][N] fp32 -> Wt[N][K] f16 ----
    const int id = bid - 6144;
    const int z = id >> 8;
    const int k0 = ((id >> 4) & 15) * 64, n0 = (id & 15) * 64;
    const float* W = (z == 0) ? Wq : (z == 1) ? Wk : (z == 2) ? Wv : Wo;
    const int r = tid >> 2, c0 = (tid & 3) * 16;
#pragma unroll
    for (int i = 0; i < 4; ++i)
      *(float4*)&sh[r][c0 + 4 * i] =
          *(const float4*)&W[(size_t)(k0 + r) * 1024 + n0 + c0 + 4 * i];
    __syncthreads();
    f16 tmp[16];
#pragma unroll
    for (int i = 0; i < 16; ++i) tmp[i] = (f16)sh[c0 + i][r];
    f16* dst = Wt + (size_t)z * 1048576 + (size_t)(n0 + r) * 1024 + k0 + c0;
    *(f16x8*)dst = *(f16x8*)&tmp[0];
    *(f16x8*)(dst + 8) = *(f16x8*)&tmp[8];
  } else if (bid < 7184) {  // ---- pack_bias ----
    const int i = (bid - 7168) * 256 + tid;
    const int z = i >> 10;
    const float* s = (z == 0) ? bq : (z == 1) ? bk : (z == 2) ? bv : bo;
    bias[i] = s[i & 1023];
  } else {  // ---- mask scan + inverse map + khc pad zero, one block/batch ----
    const int b = bid - 7184;
    int* cnt = (int*)sh;
    int loc[8];
    int c = 0;
#pragma unroll
    for (int i = 0; i < 8; ++i) {
      loc[i] = mask[b * T_ + tid * 8 + i];
      c += loc[i];
    }
    cnt[tid] = c;
    __syncthreads();
    for (int off = 1; off < 256; off <<= 1) {
      int vsh = (tid >= off) ? cnt[tid - off] : 0;
      __syncthreads();
      cnt[tid] += vsh;
      __syncthreads();
    }
    int pos = cnt[tid] - c;  // exclusive prefix
#pragma unroll
    for (int i = 0; i < 8; ++i) {
      const int t = tid * 8 + i;
      if (loc[i]) {
        idx[b * T_ + pos] = t;
        inv[b * T_ + t] = pos;
        ++pos;
      } else {
        inv[b * T_ + t] = -1;
      }
    }
    const int n = cnt[255];
    if (tid == 255) nk[b] = n;
    // zero pad rows n..nkt*64-1 of khc (gemm writes only rows < n)
    const int nkt = (n + 63) >> 6;
    const int npadrows = (nkt << 6) - n;
    uint4 z4 = {0u, 0u, 0u, 0u};
    f16* base = khc + ((size_t)b * T_ + n) * D_;
    for (int i = tid; i < npadrows * 128; i += 256)
      *(uint4*)(base + (size_t)i * 8) = z4;
  }
}

// ---------------------------------------------------------------------------
// gemm8: QKV projection GEMM, 256x256 tile, BK=32, 512 thr / 8 waves
// (per-wave 128x64). T4: ring-4 LDS (128KB), counted s_waitcnt vmcnt(12)
// (3 K-tiles always in flight, never drained in-loop), raw s_barrier.
// T2: XOR swizzle (16B chunk ^= (row>>1)&3) applied BOTH sides: pre-swizzled
// gl16 global source + swizzled ds_read -> 2-way (free) instead of 8-way
// bank conflict. T5: setprio around MFMA cluster.
// z selects slice; z==0 applies qscale; z==1 scatters rows through inv.
// Barrier scheme per iter: [issue t+3][vmcnt(12)][bar][ds_read t][mfma][bar]
//  - bar1: all waves' DMA for tile t landed before any read
//  - bar2: all reads of tile t retired before slot (t&3) is re-issued (t+4)
// ---------------------------------------------------------------------------
__global__ __launch_bounds__(512, 2) void gemm8(
    const f16* __restrict__ Xb, const f16* __restrict__ Wtb,
    const float* __restrict__ biasb, void* __restrict__ C0,
    void* __restrict__ C1, void* __restrict__ C2,
    const int* __restrict__ inv, float qscale) {
  __shared__ __align__(16) char lds[131072];  // A: 4 x 16KB | B: 4 x 16KB
  const int z = blockIdx.z;
  const f16* X  = Xb  + (size_t)z * (4096 * 1024);
  const f16* Wt = Wtb + (size_t)z * (1024 * 1024);
  const float* bias = biasb + (size_t)z * 1024;
  f16* C = (f16*)((z == 0) ? C0 : (z == 1) ? C1 : C2);
  const float scl = (z == 0) ? qscale : 1.f;

  const int tid = threadIdx.x;
  const int wave = tid >> 6, lane = tid & 63;
  const int quad = lane >> 4, l16 = lane & 15;
  const int wm = wave & 1, wn = wave >> 1;  // 2 x 4 wave grid
  const int m0 = blockIdx.y * 256, n0 = blockIdx.x * 256;

  // staging: thread covers 16B chunks tid and 512+tid of each 1024-chunk tile
  // chunk i -> row i>>2 (rounds 128 rows apart, so swizzle sel identical),
  // src chunk = (i&3) ^ ((row>>1)&3)  (involution; LDS dest stays linear)
  const int r0 = tid >> 2;
  const int ssw = (tid & 3) ^ ((r0 >> 1) & 3);
  const f16* ap0 = X  + (size_t)(m0 + r0) * 1024 + ssw * 8;
  const f16* ap1 = ap0 + (size_t)128 * 1024;
  const f16* bp0 = Wt + (size_t)(n0 + r0) * 1024 + ssw * 8;
  const f16* bp1 = bp0 + (size_t)128 * 1024;
  char* al = lds + tid * 16;
  char* bl = lds + 65536 + tid * 16;

  // read-side swizzle: frag at (row, quad) reads chunk quad ^ ((l16>>1)&3)
  const int sw16 = 16 * (quad ^ ((l16 >> 1) & 3));

  f32x4 acc[8][4] = {};

#define G8_ISSUE(tt) do {                                                   \
    const int _b = (tt) & 3; const int _ko = (tt) * 32;                     \
    gl16(ap0 + _ko, al + _b * 16384);                                       \
    gl16(ap1 + _ko, al + _b * 16384 + 8192);                                \
    gl16(bp0 + _ko, bl + _b * 16384);                                       \
    gl16(bp1 + _ko, bl + _b * 16384 + 8192);                                \
  } while (0)

#define G8_WAIT(n) asm volatile("s_waitcnt vmcnt(" #n ")" ::: "memory")

#define G8_COMPUTE(tt) do {                                                 \
    __builtin_amdgcn_s_barrier();                                           \
    const char* _Ab = lds + ((tt) & 3) * 16384;                             \
    const char* _Bb = lds + 65536 + ((tt) & 3) * 16384;                     \
    f16x8 af[8], bf[4];                                                     \
    _Pragma("unroll")                                                       \
    for (int mi = 0; mi < 8; ++mi)                                          \
      af[mi] = *(const f16x8*)(_Ab + (128 * wm + 16 * mi + l16) * 64 + sw16); \
    _Pragma("unroll")                                                       \
    for (int ni = 0; ni < 4; ++ni)                                          \
      bf[ni] = *(const f16x8*)(_Bb + (64 * wn + 16 * ni + l16) * 64 + sw16); \
    __builtin_amdgcn_s_setprio(1);                                          \
    _Pragma("unroll")                                                       \
    for (int mi = 0; mi < 8; ++mi)                                          \
      _Pragma("unroll")                                                     \
      for (int ni = 0; ni < 4; ++ni)                                        \
        acc[mi][ni] = __builtin_amdgcn_mfma_f32_16x16x32_f16(               \
            af[mi], bf[ni], acc[mi][ni], 0, 0, 0);                          \
    __builtin_amdgcn_s_setprio(0);                                          \
    __builtin_amdgcn_s_barrier();                                           \
  } while (0)

  // prologue: tiles 0,1,2 in flight (12 loads)
  G8_ISSUE(0); G8_ISSUE(1); G8_ISSUE(2);

  for (int tt = 0; tt < 29; ++tt) {  // K=1024 -> 32 K-tiles of 32
    G8_ISSUE(tt + 3);
    G8_WAIT(12);  // tile tt landed; tiles tt+1..tt+3 (12 loads) in flight
    G8_COMPUTE(tt);
  }
  G8_WAIT(8);  G8_COMPUTE(29);
  G8_WAIT(4);  G8_COMPUTE(30);
  G8_WAIT(0);  G8_COMPUTE(31);

#undef G8_ISSUE
#undef G8_WAIT
#undef G8_COMPUTE

  const int cm = m0 + 128 * wm + 4 * quad;
  const int cn = n0 + 64 * wn + l16;
  float bv[4];
#pragma unroll
  for (int ni = 0; ni < 4; ++ni) bv[ni] = bias[cn + 16 * ni];

  if (inv != nullptr && z == 1) {  // K-compaction scatter
    const int bb = m0 >> 11;
#pragma unroll
    for (int mi = 0; mi < 8; ++mi) {
#pragma unroll
      for (int r = 0; r < 4; ++r) {
        const int m = cm + 16 * mi + r;
        const int j = inv[m];
        if (j >= 0) {
          f16* row = C + ((size_t)(bb << 11) + j) * 1024;
#pragma unroll
          for (int ni = 0; ni < 4; ++ni)
            row[cn + 16 * ni] = (f16)(acc[mi][ni][r] + bv[ni]);
        }
      }
    }
  } else {
#pragma unroll
    for (int mi = 0; mi < 8; ++mi)
#pragma unroll
      for (int r = 0; r < 4; ++r) {
        f16* row = C + (size_t)(cm + 16 * mi + r) * 1024;
#pragma unroll
        for (int ni = 0; ni < 4; ++ni)
          row[cn + 16 * ni] = (f16)((acc[mi][ni][r] + bv[ni]) * scl);
      }
  }
}

// ---------------------------------------------------------------------------
// m97-style GEMM (kept for the output projection): C[M,N] = X @ Wt^T + bias.
// ---------------------------------------------------------------------------
template <int TM, typename OT>
__global__ __launch_bounds__(256) void gemm_bt(
    const f16* __restrict__ Xb, const f16* __restrict__ Wtb,
    const float* __restrict__ biasb, void* __restrict__ C0,
    void* __restrict__ C1, void* __restrict__ C2,
    const int* __restrict__ inv, int M, int N, int K, float qscale) {
  constexpr int FM = TM / 32;
  __shared__ __align__(16) f16 As[TM * 32];
  __shared__ __align__(16) f16 Bs[128 * 32];
  const int z = blockIdx.z;
  const f16* X  = Xb  + (size_t)z * M * K;
  const f16* Wt = Wtb + (size_t)z * N * K;
  const float* bias = biasb + (size_t)z * N;
  OT* C = (OT*)((z == 0) ? C0 : (z == 1) ? C1 : C2);
  const float scl = (z == 0) ? qscale : 1.f;

  const int tid = threadIdx.x;
  const int wave = tid >> 6, lane = tid & 63;
  const int quad = lane >> 4, l16 = lane & 15;
  const int wm = wave & 1, wn = wave >> 1;
  const int m0 = blockIdx.y * TM, n0 = blockIdx.x * 128;

  f32x4 acc[FM][4] = {};

  const f16* asrc = X  + (size_t)(m0 + (tid >> 2)) * K + (tid & 3) * 8;
  const f16* bsrc = Wt + (size_t)(n0 + (tid >> 2)) * K + (tid & 3) * 8;
  char* aldst = (char*)As + tid * 16;
  char* bldst = (char*)Bs + tid * 16;
  const size_t rstep = (size_t)64 * K;

  const int NK = K >> 5;
  for (int kt = 0; kt < NK; ++kt) {
    if (kt) __syncthreads();
    gl16(asrc, aldst);
    if constexpr (TM == 128) gl16(asrc + rstep, aldst + 4096);
    gl16(bsrc, bldst);
    gl16(bsrc + rstep, bldst + 4096);
    asrc += 32; bsrc += 32;
    __syncthreads();

    f16x8 af[FM], bf[4];
#pragma unroll
    for (int t = 0; t < FM; ++t)
      af[t] = *(const f16x8*)&As[((TM / 2) * wm + 16 * t + l16) * 32 + quad * 8];
#pragma unroll
    for (int t = 0; t < 4; ++t)
      bf[t] = *(const f16x8*)&Bs[(64 * wn + 16 * t + l16) * 32 + quad * 8];
#pragma unroll
    for (int i = 0; i < FM; ++i)
#pragma unroll
      for (int j = 0; j < 4; ++j)
        acc[i][j] = __builtin_amdgcn_mfma_f32_16x16x32_f16(af[i], bf[j], acc[i][j], 0, 0, 0);
  }

  const int cm = m0 + (TM / 2) * wm + 4 * quad;
  const int cn = n0 + 64 * wn + l16;
  float bv[4];
#pragma unroll
  for (int tn = 0; tn < 4; ++tn) bv[tn] = bias[cn + 16 * tn];

  if (inv != nullptr && z == 1) {  // K-compaction scatter
    const int bb = m0 >> 11;
#pragma unroll
    for (int tm = 0; tm < FM; ++tm) {
#pragma unroll
      for (int r = 0; r < 4; ++r) {
        const int m = cm + 16 * tm + r;
        const int j = inv[m];
        if (j >= 0) {
          OT* row = C + ((size_t)(bb << 11) + j) * N;
#pragma unroll
          for (int tn = 0; tn < 4; ++tn)
            row[cn + 16 * tn] = (OT)(acc[tm][tn][r] + bv[tn]);
        }
      }
    }
  } else {
#pragma unroll
    for (int tm = 0; tm < FM; ++tm)
#pragma unroll
      for (int r = 0; r < 4; ++r) {
        OT* row = C + (size_t)(cm + 16 * tm + r) * N;
#pragma unroll
        for (int tn = 0; tn < 4; ++tn)
          row[cn + 16 * tn] = (OT)((acc[tm][tn][r] + bv[tn]) * scl);
      }
  }
}

// ---------------------------------------------------------------------------
// vtrans: gather + transpose V. vhT[bh][dh][j] = vh[b][idx[j]][h*64+dh],
// zeros for pad j; tiles >= nkt untouched (attn never reads them).
// ---------------------------------------------------------------------------
__global__ __launch_bounds__(256) void vtrans(
    const f16* __restrict__ vh, const int* __restrict__ idx,
    const int* __restrict__ nk, f16* __restrict__ vhT) {
  const int tt = blockIdx.x, bh = blockIdx.y;
  const int b = bh >> 4, h = bh & 15;
  const int n = nk[b];
  const int nkt = (n + 63) >> 6;
  if (tt >= nkt) return;
  __shared__ f16 t[64][72];
  const int tid = threadIdx.x;
  const int r = tid >> 2, cq = 16 * (tid & 3);

  const int j = tt * 64 + r;
  uint4 v0 = {0u, 0u, 0u, 0u}, v1 = {0u, 0u, 0u, 0u};
  if (j < n) {
    const int tsrc = idx[b * T_ + j];
    const uint4* src = (const uint4*)(vh + ((size_t)b * T_ + tsrc) * D_ + h * 64 + cq);
    v0 = src[0]; v1 = src[1];
  }
  *(uint4*)&t[r][cq]     = v0;
  *(uint4*)&t[r][cq + 8] = v1;
  __syncthreads();

  f16 tmp[16];
#pragma unroll
  for (int xx = 0; xx < 16; ++xx) {
    int x = (xx + r) & 15;
    tmp[x] = t[cq + x][r];
  }
  f16* dst = vhT + ((size_t)bh * 64 + r) * T_ + tt * 64 + cq;
  *(uint4*)&dst[0] = *(uint4*)&tmp[0];
  *(uint4*)&dst[8] = *(uint4*)&tmp[8];
}

// ---------------------------------------------------------------------------
// Flash attention over compacted keys. Block = 128 q-rows (grid 16 x 32),
// 512 threads / 8 waves; each wave owns 16 q-rows. 16 waves/CU.
// Q frags direct from global, cached in regs. qh pre-scaled by SCALE*log2e
// -> P = exp2(S); pad keys contribute p=1, corrected via lsum -= npad.
// ---------------------------------------------------------------------------
__global__ __launch_bounds__(512) void attn_mfma(
    const f16* __restrict__ qh, const f16* __restrict__ khc,
    const f16* __restrict__ vhT, const int* __restrict__ nkd,
    f16* __restrict__ oat) {
  __shared__ f16 Ks[64][72];     // [key][dh]
  __shared__ f16 Vt[64][72];     // [dh][key]
  __shared__ f16 Ps[8][16][72];  // per-wave [qrow][key]

  const int qt = blockIdx.x, bh = blockIdx.y;
  const int b = bh >> 4, h = bh & 15;
  const int tid = threadIdx.x;
  const int wave = tid >> 6, lane = tid & 63;
  const int quad = lane >> 4, l16 = lane & 15;
  const int sr = tid >> 3, sq = 8 * (tid & 7);  // 512 thr: 1 uint4 each for K,V

  const int n = nkd[b];
  const int nkt = (n + 63) >> 6;
  const int npad = (nkt << 6) - n;

  // Q fragments direct from global: row qt*128 + wave*16 + l16
  f16x8 qf[2];
  {
    const f16* qp = qh + ((size_t)(b * T_ + qt * 128 + wave * 16 + l16)) * D_ + h * 64 + quad * 8;
    qf[0] = *(const f16x8*)qp;
    qf[1] = *(const f16x8*)(qp + 32);
  }

  float lsum = 0.f;
  f32x4 o[4] = {};

  const f16* kbase = khc + (size_t)b * T_ * D_ + h * 64;
  const f16* vbase = vhT + ((size_t)bh * 64 + sr) * T_;

  uint4 kr, vr;
  auto load_kv = [&](int kt) {
    kr = *(const uint4*)(kbase + (size_t)(kt * 64 + sr) * D_ + sq);
    vr = *(const uint4*)(vbase + kt * 64 + sq);
  };
  if (nkt > 0) load_kv(0);

  for (int kt = 0; kt < nkt; ++kt) {
    *(uint4*)&Ks[sr][sq] = kr;
    *(uint4*)&Vt[sr][sq] = vr;
    __syncthreads();
    if (kt + 1 < nkt) load_kv(kt + 1);  // prefetch next tile into regs

    // ---- S^T = K Q^T : D[m=key][n=qrow] ----
#pragma unroll
    for (int tn = 0; tn < 4; ++tn) {
      f16x8 kf0 = *(const f16x8*)&Ks[16 * tn + l16][quad * 8];
      f16x8 kf1 = *(const f16x8*)&Ks[16 * tn + l16][32 + quad * 8];
      f32x4 s = {0.f, 0.f, 0.f, 0.f};
      s = __builtin_amdgcn_mfma_f32_16x16x32_f16(kf0, qf[0], s, 0, 0, 0);
      s = __builtin_amdgcn_mfma_f32_16x16x32_f16(kf1, qf[1], s, 0, 0, 0);
      float p0 = exp2f(s[0]), p1 = exp2f(s[1]);
      float p2 = exp2f(s[2]), p3 = exp2f(s[3]);
      lsum += (p0 + p1) + (p2 + p3);
      f16x4 pk;
      pk[0] = (f16)p0; pk[1] = (f16)p1; pk[2] = (f16)p2; pk[3] = (f16)p3;
      *(f16x4*)&Ps[wave][l16][16 * tn + 4 * quad] = pk;
    }

    // ---- O += P V ----
    f16x8 pf0 = *(const f16x8*)&Ps[wave][l16][quad * 8];
    f16x8 pf1 = *(const f16x8*)&Ps[wave][l16][32 + quad * 8];
#pragma unroll
    for (int t = 0; t < 4; ++t) {
      f16x8 vf0 = *(const f16x8*)&Vt[16 * t + l16][quad * 8];
      f16x8 vf1 = *(const f16x8*)&Vt[16 * t + l16][32 + quad * 8];
      o[t] = __builtin_amdgcn_mfma_f32_16x16x32_f16(pf0, vf0, o[t], 0, 0, 0);
      o[t] = __builtin_amdgcn_mfma_f32_16x16x32_f16(pf1, vf1, o[t], 0, 0, 0);
    }
    __syncthreads();
  }

  {
    float ls = lsum;
    ls += __shfl_xor(ls, 16);   // quads hold disjoint key subsets
    ls += __shfl_xor(ls, 32);
    ls -= (float)npad;
    const size_t orow = (size_t)(b * T_ + qt * 128 + wave * 16 + 4 * quad);
#pragma unroll
    for (int r = 0; r < 4; ++r) {
      const float iv = 1.f / __shfl(ls, 4 * quad + r);
#pragma unroll
      for (int t = 0; t < 4; ++t)
        oat[(orow + r) * D_ + h * 64 + 16 * t + l16] = (f16)(o[t][r] * iv);
    }
  }
}

// ---------------------------------------------------------------------------
extern "C" void kernel_launch(void* const* d_in, const int* in_sizes, int n_in,
                              void* d_out, int out_size, void* d_ws, size_t ws_size,
                              hipStream_t stream) {
  const float* q  = (const float*)d_in[0];
  const float* k  = (const float*)d_in[1];
  const float* v  = (const float*)d_in[2];
  const int* mask = (const int*)d_in[3];
  const float* Wq = (const float*)d_in[4];
  const float* bq = (const float*)d_in[5];
  const float* Wk = (const float*)d_in[6];
  const float* bk = (const float*)d_in[7];
  const float* Wv = (const float*)d_in[8];
  const float* bv = (const float*)d_in[9];
  const float* Wo = (const float*)d_in[10];
  const float* bo = (const float*)d_in[11];
  float* out = (float*)d_out;

  // ws layout (bytes):
  //  0        xq (8MB)  -> vhT after gemm_qkv
  //  8388608  xk (8MB)  -> oat after gemm_qkv
  //  16777216 xv (8MB)
  //  25165824 Wt (8MB)
  //  33554432 qh (8MB)
  //  41943040 vh (8MB)
  //  50331648 khc (8MB)
  //  58720256 bias(16KB) | idx(16KB) | inv(16KB) | nk(8B)
  char* ws = (char*)d_ws;
  f16* xqkv  = (f16*)(ws);
  f16* Wt    = (f16*)(ws + 25165824);
  f16* qh    = (f16*)(ws + 33554432);
  f16* vh    = (f16*)(ws + 41943040);
  f16* khc   = (f16*)(ws + 50331648);
  float* bsw = (float*)(ws + 58720256);
  int* idx   = (int*)(ws + 58736640);
  int* inv   = (int*)(ws + 58753024);
  int* nk    = (int*)(ws + 58769408);
  f16* vhT   = (f16*)(ws);             // aliases xq (dead after gemm_qkv)
  f16* oat   = (f16*)(ws + 8388608);   // aliases xk (dead after gemm_qkv)

  const int M = B_ * T_;  // 4096
  dim3 blk(256);

  prep<<<dim3(7186), blk, 0, stream>>>(q, k, v, mask, Wq, Wk, Wv, Wo,
                                       bq, bk, bv, bo, xqkv, Wt, bsw,
                                       idx, inv, nk, khc);

  gemm8<<<dim3(4, 16, 3), dim3(512), 0, stream>>>(
      xqkv, Wt, bsw, qh, khc, vh, inv, QSCALE);

  vtrans<<<dim3(32, 32), blk, 0, stream>>>(vh, idx, nk, vhT);

  attn_mfma<<<dim3(16, 32), dim3(512), 0, stream>>>(qh, khc, vhT, nk, oat);

  gemm_bt<64, float><<<dim3(8, 64, 1), blk, 0, stream>>>(
      oat, Wt + 3145728, bsw + 3072, out, out, out, nullptr, M, D_, D_, 1.f);
}

// Round 4
// 223.450 us; speedup vs baseline: 1.0561x; 1.0068x over previous
//
#include <hip/hip_runtime.h>
#include <hip/hip_bf16.h>
#include <math.h>

#define B_ 2
#define T_ 2048
#define D_ 1024
#define H_ 16
#define QSCALE (0.03125f * 1.44269504088896f)  // 1/sqrt(1024) * log2(e)

typedef _Float16 f16;
using f16x4 = __attribute__((ext_vector_type(4))) _Float16;
using f16x8 = __attribute__((ext_vector_type(8))) _Float16;
using f32x4 = __attribute__((ext_vector_type(4))) float;

__device__ __forceinline__ void gl16(const void* g, void* l) {
  __builtin_amdgcn_global_load_lds(
      (__attribute__((address_space(1))) void*)g,
      (__attribute__((address_space(3))) void*)l, 16, 0, 0);
}

__device__ __forceinline__ unsigned lds_a32(const void* p) {
  return (unsigned)(size_t)(__attribute__((address_space(3))) const char*)p;
}

// ---------------------------------------------------------------------------
// prep: fused cvt_x (0..6143) + cvt_w transpose (6144..7167) + pack_bias
// (7168..7183) + mask scan -> idx/inv/nk + khc pad-row zeroing (7184..7185)
// ---------------------------------------------------------------------------
__global__ __launch_bounds__(256) void prep(
    const float* __restrict__ q, const float* __restrict__ k,
    const float* __restrict__ v, const int* __restrict__ mask,
    const float* __restrict__ Wq, const float* __restrict__ Wk,
    const float* __restrict__ Wv, const float* __restrict__ Wo,
    const float* __restrict__ bq, const float* __restrict__ bk,
    const float* __restrict__ bv, const float* __restrict__ bo,
    f16* __restrict__ xqkv, f16* __restrict__ Wt, float* __restrict__ bias,
    int* __restrict__ idx, int* __restrict__ inv, int* __restrict__ nk,
    f16* __restrict__ khc) {
  __shared__ float sh[64][65];
  const int bid = blockIdx.x;
  const int tid = threadIdx.x;

  if (bid < 6144) {  // ---- cvt_x: fp32 -> f16 ----
    const int z = bid / 2048;
    const float* src = (z == 0) ? q : (z == 1) ? k : v;
    const size_t i = ((size_t)(bid % 2048) * 256 + tid) * 8;
    float4 a = *(const float4*)(src + i);
    float4 b = *(const float4*)(src + i + 4);
    f16x8 o;
    o[0] = (f16)a.x; o[1] = (f16)a.y; o[2] = (f16)a.z; o[3] = (f16)a.w;
    o[4] = (f16)b.x; o[5] = (f16)b.y; o[6] = (f16)b.z; o[7] = (f16)b.w;
    *(f16x8*)(xqkv + (size_t)z * 4194304 + i) = o;
  } else if (bid < 7168) {  // ---- cvt_w: W[K][N] fp32 -> Wt[N][K] f16 ----
    const int id = bid - 6144;
    const int z = id >> 8;
    const int k0 = ((id >> 4) & 15) * 64, n0 = (id & 15) * 64;
    const float* W = (z == 0) ? Wq : (z == 1) ? Wk : (z == 2) ? Wv : Wo;
    const int r = tid >> 2, c0 = (tid & 3) * 16;
#pragma unroll
    for (int i = 0; i < 4; ++i)
      *(float4*)&sh[r][c0 + 4 * i] =
          *(const float4*)&W[(size_t)(k0 + r) * 1024 + n0 + c0 + 4 * i];
    __syncthreads();
    f16 tmp[16];
#pragma unroll
    for (int i = 0; i < 16; ++i) tmp[i] = (f16)sh[c0 + i][r];
    f16* dst = Wt + (size_t)z * 1048576 + (size_t)(n0 + r) * 1024 + k0 + c0;
    *(f16x8*)dst = *(f16x8*)&tmp[0];
    *(f16x8*)(dst + 8) = *(f16x8*)&tmp[8];
  } else if (bid < 7184) {  // ---- pack_bias ----
    const int i = (bid - 7168) * 256 + tid;
    const int z = i >> 10;
    const float* s = (z == 0) ? bq : (z == 1) ? bk : (z == 2) ? bv : bo;
    bias[i] = s[i & 1023];
  } else {  // ---- mask scan + inverse map + khc pad zero, one block/batch ----
    const int b = bid - 7184;
    int* cnt = (int*)sh;
    int loc[8];
    int c = 0;
#pragma unroll
    for (int i = 0; i < 8; ++i) {
      loc[i] = mask[b * T_ + tid * 8 + i];
      c += loc[i];
    }
    cnt[tid] = c;
    __syncthreads();
    for (int off = 1; off < 256; off <<= 1) {
      int vsh = (tid >= off) ? cnt[tid - off] : 0;
      __syncthreads();
      cnt[tid] += vsh;
      __syncthreads();
    }
    int pos = cnt[tid] - c;  // exclusive prefix
#pragma unroll
    for (int i = 0; i < 8; ++i) {
      const int t = tid * 8 + i;
      if (loc[i]) {
        idx[b * T_ + pos] = t;
        inv[b * T_ + t] = pos;
        ++pos;
      } else {
        inv[b * T_ + t] = -1;
      }
    }
    const int n = cnt[255];
    if (tid == 255) nk[b] = n;
    // zero pad rows n..nkt*64-1 of khc (gemm writes only rows < n)
    const int nkt = (n + 63) >> 6;
    const int npadrows = (nkt << 6) - n;
    uint4 z4 = {0u, 0u, 0u, 0u};
    f16* base = khc + ((size_t)b * T_ + n) * D_;
    for (int i = tid; i < npadrows * 128; i += 256)
      *(uint4*)(base + (size_t)i * 8) = z4;
  }
}

// ---------------------------------------------------------------------------
// gemm8: QKV projection GEMM, 256x256 tile, BK=32, 512 thr / 8 waves
// (per-wave 128x64). Ring-4 LDS (128KB), counted s_waitcnt vmcnt(12)
// (3 K-tiles always in flight, never drained in-loop), raw s_barrier.
// Fragment loads are inline-asm ds_read_b128 -> opaque to SIInsertWaitcnts,
// so the compiler cannot insert its own vmcnt(0) drain before the LDS reads
// (which defeated the ring in round 2). Addresses are plain uint32 VGPRs;
// offsets are baked into the asm STRING (no "n" operands -> no backend
// immediate-printing issues, the prime suspect for round 3's build failure).
// Manual lgkmcnt(6)/lgkmcnt(0) + sched_barrier(0) order the MFMAs (rule #18).
// XOR swizzle both-sides as before (0 bank conflicts in round 2).
// Barrier scheme per iter: [issue t+3][vmcnt(12)][bar][ds_read t][mfma][bar]
//  - bar1: every wave passed its own vmcnt -> all tile-t DMA landed
//  - bar2: lgkmcnt(0) before it -> all reads of slot t&3 retired before
//    that slot is re-issued at iter t+1 (tile t+4)
// ---------------------------------------------------------------------------
__global__ __launch_bounds__(512, 2) void gemm8(
    const f16* __restrict__ Xb, const f16* __restrict__ Wtb,
    const float* __restrict__ biasb, void* __restrict__ C0,
    void* __restrict__ C1, void* __restrict__ C2,
    const int* __restrict__ inv, float qscale) {
  __shared__ __align__(16) char lds[131072];  // A: 4 x 16KB | B: 4 x 16KB
  const int z = blockIdx.z;
  const f16* X  = Xb  + (size_t)z * (4096 * 1024);
  const f16* Wt = Wtb + (size_t)z * (1024 * 1024);
  const float* bias = biasb + (size_t)z * 1024;
  f16* C = (f16*)((z == 0) ? C0 : (z == 1) ? C1 : C2);
  const float scl = (z == 0) ? qscale : 1.f;

  const int tid = threadIdx.x;
  const int wave = tid >> 6, lane = tid & 63;
  const int quad = lane >> 4, l16 = lane & 15;
  const int wm = wave & 1, wn = wave >> 1;  // 2 x 4 wave grid
  const int m0 = blockIdx.y * 256, n0 = blockIdx.x * 256;

  // staging: thread covers 16B chunks tid and 512+tid of each 1024-chunk tile
  // chunk i -> row i>>2, src chunk = (i&3) ^ ((row>>1)&3)  (involution;
  // LDS dest stays linear as global_load_lds requires)
  const int r0 = tid >> 2;
  const int ssw = (tid & 3) ^ ((r0 >> 1) & 3);
  const f16* ap0 = X  + (size_t)(m0 + r0) * 1024 + ssw * 8;
  const f16* ap1 = ap0 + (size_t)128 * 1024;
  const f16* bp0 = Wt + (size_t)(n0 + r0) * 1024 + ssw * 8;
  const f16* bp1 = bp0 + (size_t)128 * 1024;
  char* al = lds + tid * 16;
  char* bl = lds + 65536 + tid * 16;

  // read-side swizzle: frag at (row, quad) reads chunk quad ^ ((l16>>1)&3)
  const int sw16 = 16 * (quad ^ ((l16 >> 1) & 3));

  // asm ds_read base addresses as 32-bit LDS byte offsets (slot 0, frag 0)
  const unsigned a32 = lds_a32(lds + (128 * wm + l16) * 64 + sw16);
  const unsigned b32 = lds_a32(lds + 65536 + (64 * wn + l16) * 64 + sw16);

  f32x4 acc[8][4] = {};

#define G8_ISSUE(tt, sl) do {                                               \
    gl16(ap0 + (tt) * 32, al + (sl) * 16384);                               \
    gl16(ap1 + (tt) * 32, al + (sl) * 16384 + 8192);                        \
    gl16(bp0 + (tt) * 32, bl + (sl) * 16384);                               \
    gl16(bp1 + (tt) * 32, bl + (sl) * 16384 + 8192);                        \
  } while (0)

#define G8_WAIT(n) asm volatile("s_waitcnt vmcnt(" #n ")" ::: "memory")

#define G8_STR_(x) #x
#define G8_STR(x) G8_STR_(x)
#define DSR(dst, base, OFF)                                                 \
  asm volatile("ds_read_b128 %0, %1 offset:" G8_STR(OFF)                    \
               : "=v"(dst) : "v"(base))

#define G8_COMPUTE(sl) do {                                                 \
    __builtin_amdgcn_s_barrier();                                           \
    const unsigned aa = a32 + (sl) * 16384;                                 \
    const unsigned bb = b32 + (sl) * 16384;                                 \
    f16x8 af[8], bf[4];                                                     \
    DSR(af[0], aa, 0);    DSR(af[1], aa, 1024);                             \
    DSR(bf[0], bb, 0);    DSR(bf[1], bb, 1024);                             \
    DSR(bf[2], bb, 2048); DSR(bf[3], bb, 3072);                             \
    DSR(af[2], aa, 2048); DSR(af[3], aa, 3072);                             \
    DSR(af[4], aa, 4096); DSR(af[5], aa, 5120);                             \
    DSR(af[6], aa, 6144); DSR(af[7], aa, 7168);                             \
    asm volatile("s_waitcnt lgkmcnt(6)" ::: "memory");                      \
    __builtin_amdgcn_sched_barrier(0);                                      \
    __builtin_amdgcn_s_setprio(1);                                          \
    _Pragma("unroll")                                                       \
    for (int mi = 0; mi < 2; ++mi)                                          \
      _Pragma("unroll")                                                     \
      for (int ni = 0; ni < 4; ++ni)                                        \
        acc[mi][ni] = __builtin_amdgcn_mfma_f32_16x16x32_f16(               \
            af[mi], bf[ni], acc[mi][ni], 0, 0, 0);                          \
    asm volatile("s_waitcnt lgkmcnt(0)" ::: "memory");                      \
    __builtin_amdgcn_sched_barrier(0);                                      \
    _Pragma("unroll")                                                       \
    for (int mi = 2; mi < 8; ++mi)                                          \
      _Pragma("unroll")                                                     \
      for (int ni = 0; ni < 4; ++ni)                                        \
        acc[mi][ni] = __builtin_amdgcn_mfma_f32_16x16x32_f16(               \
            af[mi], bf[ni], acc[mi][ni], 0, 0, 0);                          \
    __builtin_amdgcn_s_setprio(0);                                          \
    __builtin_amdgcn_s_barrier();                                           \
  } while (0)

  // prologue: tiles 0,1,2 in flight (12 loads/wave)
  G8_ISSUE(0, 0); G8_ISSUE(1, 1); G8_ISSUE(2, 2);

  for (int j = 0; j < 7; ++j) {  // tt = 4j .. 4j+3  (0..27)
    const int t4 = j * 4;
    G8_ISSUE(t4 + 3, 3); G8_WAIT(12); G8_COMPUTE(0);
    G8_ISSUE(t4 + 4, 0); G8_WAIT(12); G8_COMPUTE(1);
    G8_ISSUE(t4 + 5, 1); G8_WAIT(12); G8_COMPUTE(2);
    G8_ISSUE(t4 + 6, 2); G8_WAIT(12); G8_COMPUTE(3);
  }
  G8_ISSUE(31, 3); G8_WAIT(12); G8_COMPUTE(0);  // tt=28
  G8_WAIT(8);  G8_COMPUTE(1);                   // tt=29
  G8_WAIT(4);  G8_COMPUTE(2);                   // tt=30
  G8_WAIT(0);  G8_COMPUTE(3);                   // tt=31

#undef G8_ISSUE
#undef G8_WAIT
#undef DSR
#undef G8_STR
#undef G8_STR_
#undef G8_COMPUTE

  const int cm = m0 + 128 * wm + 4 * quad;
  const int cn = n0 + 64 * wn + l16;
  float bv[4];
#pragma unroll
  for (int ni = 0; ni < 4; ++ni) bv[ni] = bias[cn + 16 * ni];

  if (inv != nullptr && z == 1) {  // K-compaction scatter
    const int bb = m0 >> 11;
#pragma unroll
    for (int mi = 0; mi < 8; ++mi) {
#pragma unroll
      for (int r = 0; r < 4; ++r) {
        const int m = cm + 16 * mi + r;
        const int j = inv[m];
        if (j >= 0) {
          f16* row = C + ((size_t)(bb << 11) + j) * 1024;
#pragma unroll
          for (int ni = 0; ni < 4; ++ni)
            row[cn + 16 * ni] = (f16)(acc[mi][ni][r] + bv[ni]);
        }
      }
    }
  } else {
#pragma unroll
    for (int mi = 0; mi < 8; ++mi)
#pragma unroll
      for (int r = 0; r < 4; ++r) {
        f16* row = C + (size_t)(cm + 16 * mi + r) * 1024;
#pragma unroll
        for (int ni = 0; ni < 4; ++ni)
          row[cn + 16 * ni] = (f16)((acc[mi][ni][r] + bv[ni]) * scl);
      }
  }
}

// ---------------------------------------------------------------------------
// m97-style GEMM (kept for the output projection): C[M,N] = X @ Wt^T + bias.
// ---------------------------------------------------------------------------
template <int TM, typename OT>
__global__ __launch_bounds__(256) void gemm_bt(
    const f16* __restrict__ Xb, const f16* __restrict__ Wtb,
    const float* __restrict__ biasb, void* __restrict__ C0,
    void* __restrict__ C1, void* __restrict__ C2,
    const int* __restrict__ inv, int M, int N, int K, float qscale) {
  constexpr int FM = TM / 32;
  __shared__ __align__(16) f16 As[TM * 32];
  __shared__ __align__(16) f16 Bs[128 * 32];
  const int z = blockIdx.z;
  const f16* X  = Xb  + (size_t)z * M * K;
  const f16* Wt = Wtb + (size_t)z * N * K;
  const float* bias = biasb + (size_t)z * N;
  OT* C = (OT*)((z == 0) ? C0 : (z == 1) ? C1 : C2);
  const float scl = (z == 0) ? qscale : 1.f;

  const int tid = threadIdx.x;
  const int wave = tid >> 6, lane = tid & 63;
  const int quad = lane >> 4, l16 = lane & 15;
  const int wm = wave & 1, wn = wave >> 1;
  const int m0 = blockIdx.y * TM, n0 = blockIdx.x * 128;

  f32x4 acc[FM][4] = {};

  const f16* asrc = X  + (size_t)(m0 + (tid >> 2)) * K + (tid & 3) * 8;
  const f16* bsrc = Wt + (size_t)(n0 + (tid >> 2)) * K + (tid & 3) * 8;
  char* aldst = (char*)As + tid * 16;
  char* bldst = (char*)Bs + tid * 16;
  const size_t rstep = (size_t)64 * K;

  const int NK = K >> 5;
  for (int kt = 0; kt < NK; ++kt) {
    if (kt) __syncthreads();
    gl16(asrc, aldst);
    if constexpr (TM == 128) gl16(asrc + rstep, aldst + 4096);
    gl16(bsrc, bldst);
    gl16(bsrc + rstep, bldst + 4096);
    asrc += 32; bsrc += 32;
    __syncthreads();

    f16x8 af[FM], bf[4];
#pragma unroll
    for (int t = 0; t < FM; ++t)
      af[t] = *(const f16x8*)&As[((TM / 2) * wm + 16 * t + l16) * 32 + quad * 8];
#pragma unroll
    for (int t = 0; t < 4; ++t)
      bf[t] = *(const f16x8*)&Bs[(64 * wn + 16 * t + l16) * 32 + quad * 8];
#pragma unroll
    for (int i = 0; i < FM; ++i)
#pragma unroll
      for (int j = 0; j < 4; ++j)
        acc[i][j] = __builtin_amdgcn_mfma_f32_16x16x32_f16(af[i], bf[j], acc[i][j], 0, 0, 0);
  }

  const int cm = m0 + (TM / 2) * wm + 4 * quad;
  const int cn = n0 + 64 * wn + l16;
  float bv[4];
#pragma unroll
  for (int tn = 0; tn < 4; ++tn) bv[tn] = bias[cn + 16 * tn];

  if (inv != nullptr && z == 1) {  // K-compaction scatter
    const int bb = m0 >> 11;
#pragma unroll
    for (int tm = 0; tm < FM; ++tm) {
#pragma unroll
      for (int r = 0; r < 4; ++r) {
        const int m = cm + 16 * tm + r;
        const int j = inv[m];
        if (j >= 0) {
          OT* row = C + ((size_t)(bb << 11) + j) * N;
#pragma unroll
          for (int tn = 0; tn < 4; ++tn)
            row[cn + 16 * tn] = (OT)(acc[tm][tn][r] + bv[tn]);
        }
      }
    }
  } else {
#pragma unroll
    for (int tm = 0; tm < FM; ++tm)
#pragma unroll
      for (int r = 0; r < 4; ++r) {
        OT* row = C + (size_t)(cm + 16 * tm + r) * N;
#pragma unroll
        for (int tn = 0; tn < 4; ++tn)
          row[cn + 16 * tn] = (OT)((acc[tm][tn][r] + bv[tn]) * scl);
      }
  }
}

// ---------------------------------------------------------------------------
// vtrans: gather + transpose V. vhT[bh][dh][j] = vh[b][idx[j]][h*64+dh],
// zeros for pad j; tiles >= nkt untouched (attn never reads them).
// ---------------------------------------------------------------------------
__global__ __launch_bounds__(256) void vtrans(
    const f16* __restrict__ vh, const int* __restrict__ idx,
    const int* __restrict__ nk, f16* __restrict__ vhT) {
  const int tt = blockIdx.x, bh = blockIdx.y;
  const int b = bh >> 4, h = bh & 15;
  const int n = nk[b];
  const int nkt = (n + 63) >> 6;
  if (tt >= nkt) return;
  __shared__ f16 t[64][72];
  const int tid = threadIdx.x;
  const int r = tid >> 2, cq = 16 * (tid & 3);

  const int j = tt * 64 + r;
  uint4 v0 = {0u, 0u, 0u, 0u}, v1 = {0u, 0u, 0u, 0u};
  if (j < n) {
    const int tsrc = idx[b * T_ + j];
    const uint4* src = (const uint4*)(vh + ((size_t)b * T_ + tsrc) * D_ + h * 64 + cq);
    v0 = src[0]; v1 = src[1];
  }
  *(uint4*)&t[r][cq]     = v0;
  *(uint4*)&t[r][cq + 8] = v1;
  __syncthreads();

  f16 tmp[16];
#pragma unroll
  for (int xx = 0; xx < 16; ++xx) {
    int x = (xx + r) & 15;
    tmp[x] = t[cq + x][r];
  }
  f16* dst = vhT + ((size_t)bh * 64 + r) * T_ + tt * 64 + cq;
  *(uint4*)&dst[0] = *(uint4*)&tmp[0];
  *(uint4*)&dst[8] = *(uint4*)&tmp[8];
}

// ---------------------------------------------------------------------------
// Flash attention over compacted keys. Block = 128 q-rows (grid 16 x 32),
// 512 threads / 8 waves; each wave owns 16 q-rows. 16 waves/CU.
// Q frags direct from global, cached in regs. qh pre-scaled by SCALE*log2e
// -> P = exp2(S); pad keys contribute p=1, corrected via lsum -= npad.
// ---------------------------------------------------------------------------
__global__ __launch_bounds__(512) void attn_mfma(
    const f16* __restrict__ qh, const f16* __restrict__ khc,
    const f16* __restrict__ vhT, const int* __restrict__ nkd,
    f16* __restrict__ oat) {
  __shared__ f16 Ks[64][72];     // [key][dh]
  __shared__ f16 Vt[64][72];     // [dh][key]
  __shared__ f16 Ps[8][16][72];  // per-wave [qrow][key]

  const int qt = blockIdx.x, bh = blockIdx.y;
  const int b = bh >> 4, h = bh & 15;
  const int tid = threadIdx.x;
  const int wave = tid >> 6, lane = tid & 63;
  const int quad = lane >> 4, l16 = lane & 15;
  const int sr = tid >> 3, sq = 8 * (tid & 7);  // 512 thr: 1 uint4 each for K,V

  const int n = nkd[b];
  const int nkt = (n + 63) >> 6;
  const int npad = (nkt << 6) - n;

  // Q fragments direct from global: row qt*128 + wave*16 + l16
  f16x8 qf[2];
  {
    const f16* qp = qh + ((size_t)(b * T_ + qt * 128 + wave * 16 + l16)) * D_ + h * 64 + quad * 8;
    qf[0] = *(const f16x8*)qp;
    qf[1] = *(const f16x8*)(qp + 32);
  }

  float lsum = 0.f;
  f32x4 o[4] = {};

  const f16* kbase = khc + (size_t)b * T_ * D_ + h * 64;
  const f16* vbase = vhT + ((size_t)bh * 64 + sr) * T_;

  uint4 kr, vr;
  auto load_kv = [&](int kt) {
    kr = *(const uint4*)(kbase + (size_t)(kt * 64 + sr) * D_ + sq);
    vr = *(const uint4*)(vbase + kt * 64 + sq);
  };
  if (nkt > 0) load_kv(0);

  for (int kt = 0; kt < nkt; ++kt) {
    *(uint4*)&Ks[sr][sq] = kr;
    *(uint4*)&Vt[sr][sq] = vr;
    __syncthreads();
    if (kt + 1 < nkt) load_kv(kt + 1);  // prefetch next tile into regs

    // ---- S^T = K Q^T : D[m=key][n=qrow] ----
#pragma unroll
    for (int tn = 0; tn < 4; ++tn) {
      f16x8 kf0 = *(const f16x8*)&Ks[16 * tn + l16][quad * 8];
      f16x8 kf1 = *(const f16x8*)&Ks[16 * tn + l16][32 + quad * 8];
      f32x4 s = {0.f, 0.f, 0.f, 0.f};
      s = __builtin_amdgcn_mfma_f32_16x16x32_f16(kf0, qf[0], s, 0, 0, 0);
      s = __builtin_amdgcn_mfma_f32_16x16x32_f16(kf1, qf[1], s, 0, 0, 0);
      float p0 = exp2f(s[0]), p1 = exp2f(s[1]);
      float p2 = exp2f(s[2]), p3 = exp2f(s[3]);
      lsum += (p0 + p1) + (p2 + p3);
      f16x4 pk;
      pk[0] = (f16)p0; pk[1] = (f16)p1; pk[2] = (f16)p2; pk[3] = (f16)p3;
      *(f16x4*)&Ps[wave][l16][16 * tn + 4 * quad] = pk;
    }

    // ---- O += P V ----
    f16x8 pf0 = *(const f16x8*)&Ps[wave][l16][quad * 8];
    f16x8 pf1 = *(const f16x8*)&Ps[wave][l16][32 + quad * 8];
#pragma unroll
    for (int t = 0; t < 4; ++t) {
      f16x8 vf0 = *(const f16x8*)&Vt[16 * t + l16][quad * 8];
      f16x8 vf1 = *(const f16x8*)&Vt[16 * t + l16][32 + quad * 8];
      o[t] = __builtin_amdgcn_mfma_f32_16x16x32_f16(pf0, vf0, o[t], 0, 0, 0);
      o[t] = __builtin_amdgcn_mfma_f32_16x16x32_f16(pf1, vf1, o[t], 0, 0, 0);
    }
    __syncthreads();
  }

  {
    float ls = lsum;
    ls += __shfl_xor(ls, 16);   // quads hold disjoint key subsets
    ls += __shfl_xor(ls, 32);
    ls -= (float)npad;
    const size_t orow = (size_t)(b * T_ + qt * 128 + wave * 16 + 4 * quad);
#pragma unroll
    for (int r = 0; r < 4; ++r) {
      const float iv = 1.f / __shfl(ls, 4 * quad + r);
#pragma unroll
      for (int t = 0; t < 4; ++t)
        oat[(orow + r) * D_ + h * 64 + 16 * t + l16] = (f16)(o[t][r] * iv);
    }
  }
}

// ---------------------------------------------------------------------------
extern "C" void kernel_launch(void* const* d_in, const int* in_sizes, int n_in,
                              void* d_out, int out_size, void* d_ws, size_t ws_size,
                              hipStream_t stream) {
  const float* q  = (const float*)d_in[0];
  const float* k  = (const float*)d_in[1];
  const float* v  = (const float*)d_in[2];
  const int* mask = (const int*)d_in[3];
  const float* Wq = (const float*)d_in[4];
  const float* bq = (const float*)d_in[5];
  const float* Wk = (const float*)d_in[6];
  const float* bk = (const float*)d_in[7];
  const float* Wv = (const float*)d_in[8];
  const float* bv = (const float*)d_in[9];
  const float* Wo = (const float*)d_in[10];
  const float* bo = (const float*)d_in[11];
  float* out = (float*)d_out;

  // ws layout (bytes):
  //  0        xq (8MB)  -> vhT after gemm_qkv
  //  8388608  xk (8MB)  -> oat after gemm_qkv
  //  16777216 xv (8MB)
  //  25165824 Wt (8MB)
  //  33554432 qh (8MB)
  //  41943040 vh (8MB)
  //  50331648 khc (8MB)
  //  58720256 bias(16KB) | idx(16KB) | inv(16KB) | nk(8B)
  char* ws = (char*)d_ws;
  f16* xqkv  = (f16*)(ws);
  f16* Wt    = (f16*)(ws + 25165824);
  f16* qh    = (f16*)(ws + 33554432);
  f16* vh    = (f16*)(ws + 41943040);
  f16* khc   = (f16*)(ws + 50331648);
  float* bsw = (float*)(ws + 58720256);
  int* idx   = (int*)(ws + 58736640);
  int* inv   = (int*)(ws + 58753024);
  int* nk    = (int*)(ws + 58769408);
  f16* vhT   = (f16*)(ws);             // aliases xq (dead after gemm_qkv)
  f16* oat   = (f16*)(ws + 8388608);   // aliases xk (dead after gemm_qkv)

  const int M = B_ * T_;  // 4096
  dim3 blk(256);

  prep<<<dim3(7186), blk, 0, stream>>>(q, k, v, mask, Wq, Wk, Wv, Wo,
                                       bq, bk, bv, bo, xqkv, Wt, bsw,
                                       idx, inv, nk, khc);

  gemm8<<<dim3(4, 16, 3), dim3(512), 0, stream>>>(
      xqkv, Wt, bsw, qh, khc, vh, inv, QSCALE);

  vtrans<<<dim3(32, 32), blk, 0, stream>>>(vh, idx, nk, vhT);

  attn_mfma<<<dim3(16, 32), dim3(512), 0, stream>>>(qh, khc, vhT, nk, oat);

  gemm_bt<64, float><<<dim3(8, 64, 1), blk, 0, stream>>>(
      oat, Wt + 3145728, bsw + 3072, out, out, out, nullptr, M, D_, D_, 1.f);
}